// Round 5
// baseline (9118.571 us; speedup 1.0000x reference)
//
#include <hip/hip_runtime.h>

#define HH 64
#define WW 64
#define HWSZ 4096
#define BB 4
#define SS 16

// ---- direct 3x3 conv, pad 1: x (N,CI,H,W) f32 -> y (N,KO,H,W) f32 ---------
// wgt (KO,CI,3,3) f32, bias (KO) f32 or nullptr.
// grid (H/4, KO, N), block 256 (4 rows x 64 cols).
template<int CI>
__global__ void conv3x3_kernel(const float* __restrict__ x, const float* __restrict__ wgt,
                               const float* __restrict__ bias, float* __restrict__ y) {
    __shared__ float wl[CI * 9];
    const int ko = blockIdx.y;
    const int n  = blockIdx.z;
    const int t  = threadIdx.x;
    for (int i = t; i < CI * 9; i += 256) wl[i] = wgt[ko * CI * 9 + i];
    __syncthreads();
    const int h = blockIdx.x * 4 + (t >> 6);
    const int w = t & 63;
    const float* xb = x + (size_t)n * CI * HWSZ;
    float acc = bias ? bias[ko] : 0.0f;
    for (int ci = 0; ci < CI; ++ci) {
        const float* xc = xb + ci * HWSZ;
        const float* wc = wl + ci * 9;
#pragma unroll
        for (int dy = 0; dy < 3; ++dy) {
            const int hy = h + dy - 1;
            if (hy < 0 || hy >= HH) continue;
            const float* xr = xc + hy * WW;
#pragma unroll
            for (int dx = 0; dx < 3; ++dx) {
                const int wx = w + dx - 1;
                if (wx >= 0 && wx < WW) acc = fmaf(xr[wx], wc[dy * 3 + dx], acc);
            }
        }
    }
    y[((size_t)n * gridDim.y + ko) * HWSZ + h * WW + w] = acc;
}

// ---- minGRU scan + residual, one batch ------------------------------------
// y (S,128,HW) f32: gate ch [0,64), hidden ch [64,128).
// res/out (S,64,HW) f32, may alias (same thread reads res[ob] then writes out[ob]).
// hlast (64,HW) f32 = scan value at s=S-1 (pre-residual). One thread per (c,hw).
__global__ void gru_kernel(const float* __restrict__ y, const float* __restrict__ res,
                           float* __restrict__ out, float* __restrict__ hlast) {
    const int tid = blockIdx.x * 256 + threadIdx.x;   // over 64*4096
    const int c   = tid >> 12;
    const int hw  = tid & 4095;
    float h = 0.5f;
#pragma unroll 4
    for (int s = 0; s < SS; ++s) {
        const size_t yb = ((size_t)(s * 128 + c)) * HWSZ + hw;
        const float g   = y[yb];
        const float hid = y[yb + 64 * HWSZ];
        const float z   = 1.0f / (1.0f + __expf(-g));
        const float gg  = (hid >= 0.0f) ? (hid + 0.5f) : (1.0f / (1.0f + __expf(-hid)));
        h = h + z * (gg - h);                          // (1-z)*h + z*gg
        const size_t ob = ((size_t)(s * 64 + c)) * HWSZ + hw;
        const float r = res[ob];                       // read before (possibly aliased) write
        out[ob] = h + r;
    }
    hlast[tid] = h;
}

extern "C" void kernel_launch(void* const* d_in, const int* in_sizes, int n_in,
                              void* d_out, int out_size, void* d_ws, size_t ws_size,
                              hipStream_t stream) {
    const float* x  = (const float*)d_in[0];   // (4,16,32,64,64)
    const float* W0 = (const float*)d_in[1];   // (128,32,3,3)
    const float* b0 = (const float*)d_in[2];   // (128,)
    const float* R0 = (const float*)d_in[3];   // (64,32,3,3)
    const float* W1 = (const float*)d_in[4];   // (128,64,3,3)
    const float* b1 = (const float*)d_in[5];   // (128,)

    float* out = (float*)d_out;                 // (4,16,64,64,64) = 16,777,216
    float* h0o = out + (size_t)16777216;        // (4,1,64,64,64)  = 1,048,576
    float* h1o = h0o + (size_t)1048576;

    char* ws = (char*)d_ws;
    float* y0 = (float*)ws;                             // S*128*HW f32 = 32 MiB
    float* r0 = (float*)(ws + ((size_t)32 << 20));      // S*64*HW  f32 = 16 MiB
    // total ws used = 48 MiB

    for (int b = 0; b < BB; ++b) {
        const float* xb = x + (size_t)b * SS * 32 * HWSZ;

        // Layer 0: gate/hidden conv + residual conv + scan (x1 stored in-place in r0)
        conv3x3_kernel<32><<<dim3(16, 128, SS), 256, 0, stream>>>(xb, W0, b0, y0);
        conv3x3_kernel<32><<<dim3(16, 64,  SS), 256, 0, stream>>>(xb, R0, nullptr, r0);
        gru_kernel<<<1024, 256, 0, stream>>>(y0, r0, r0, h0o + (size_t)b * 262144);

        // Layer 1: conv (y1 reuses y0) + scan with identity residual (res = x1 = r0)
        conv3x3_kernel<64><<<dim3(16, 128, SS), 256, 0, stream>>>(r0, W1, b1, y0);
        gru_kernel<<<1024, 256, 0, stream>>>(y0, r0,
                                             out + (size_t)b * 4194304,
                                             h1o + (size_t)b * 262144);
    }
}

// Round 7
// 502.721 us; speedup vs baseline: 18.1384x; 18.1384x over previous
//
#include <hip/hip_runtime.h>

typedef short short8  __attribute__((ext_vector_type(8)));
typedef short shortx4 __attribute__((ext_vector_type(4)));
typedef float floatx4 __attribute__((ext_vector_type(4)));
typedef unsigned short u16;

static __device__ __forceinline__ float bits2f(u16 s) {
    return __builtin_bit_cast(float, (unsigned)s << 16);
}
static __device__ __forceinline__ u16 f2bits(float f) {
    return __builtin_bit_cast(u16, (__bf16)f);   // RNE
}
template<typename T> static __device__ __forceinline__ float loadf(T v);
template<> __device__ __forceinline__ float loadf<float>(float v) { return v; }
template<> __device__ __forceinline__ float loadf<u16>(u16 v) { return bits2f(v); }

#define SS 16

// ---- weight prepack (all layers) + zero-bias, one kernel ------------------
// wt layout: [tap][ko][ci] bf16.
__global__ void prep_kernel(const float* W0, const float* R0, const float* W1,
                            u16* wt0, u16* wtR, u16* wt1, float* zb) {
    const int i = blockIdx.x * 256 + threadIdx.x;
    if (i < 36864) {
        const int t = i / 4096, r = i % 4096, ko = r >> 5, ci = r & 31;
        wt0[i] = f2bits(W0[(ko * 32 + ci) * 9 + t]);
    } else if (i < 36864 + 18432) {
        const int j = i - 36864;
        const int t = j / 2048, r = j % 2048, ko = r >> 5, ci = r & 31;
        wtR[j] = f2bits(R0[(ko * 32 + ci) * 9 + t]);
    } else if (i < 36864 + 18432 + 73728) {
        const int j = i - 36864 - 18432;
        const int t = j / 8192, r = j % 8192, ko = r >> 6, ci = r & 63;
        wt1[j] = f2bits(W1[(ko * 64 + ci) * 9 + t]);
    } else if (i < 36864 + 18432 + 73728 + 64) {
        zb[i - 129024] = 0.0f;
    }
}

// ---- MFMA implicit-GEMM 3x3 conv, pad 1 -----------------------------------
// X (n_img, CI, 64, 64) of T; wt [9][KO][CI] bf16; bias (KO) f32 (never null);
// Y (n_img, KO, 64, 64) bf16. Block 256 = 4 waves; one image x 4-row strip.
// grid(16 strips, n_img). Wave: KPW=KO/64 ko-groups x 16 pixel-groups.
template<typename T, int CI, int KO>
__global__ __launch_bounds__(256, 2)
void conv3x3_mfma_kernel(const T* X, const u16* wt, const float* bias, u16* Y) {
    constexpr int CG  = CI / 8;    // 16B ci-granules per (row,col)
    constexpr int KPW = KO / 64;
    __shared__ short8 lds[6 * 66 * CG];

    const int l   = threadIdx.x & 63;
    const int wv  = threadIdx.x >> 6;
    const int c16 = l & 15;
    const int q16 = l >> 4;
    const int h0  = blockIdx.x * 4;
    const int n   = blockIdx.y;
    const T* Xn = X + (size_t)n * CI * 4096;

    // zero ALL of LDS (borders + out-of-range rows stay zero)
    {
        const short8 z = {0, 0, 0, 0, 0, 0, 0, 0};
        for (int i = threadIdx.x; i < 6 * 66 * CG; i += 256) lds[i] = z;
    }
    __syncthreads();

    // stage rows h0-1..h0+4, cols 1..64 (bf16, ci-granule contiguous, linear)
    for (int task = wv; task < 24; task += 4) {
        const int r  = task >> 2;
        const int wb = (task & 3) << 4;
        const int h  = h0 + r - 1;
        if (h >= 0 && h < 64) {
            const int col = 1 + wb + c16;
#pragma unroll
            for (int ji = 0; ji < CG / 4; ++ji) {
                const int q = ji * 4 + q16;
                const T* src = Xn + (size_t)(q * 8) * 4096 + h * 64 + wb + c16;
                short8 v;
#pragma unroll
                for (int j = 0; j < 8; ++j) v[j] = (short)f2bits(loadf<T>(src[(size_t)j * 4096]));
                lds[(r * 66 + col) * CG + q] = v;
            }
        }
    }
    __syncthreads();

    const int kogb = wv * KPW;
    floatx4 acc[KPW][16];
#pragma unroll
    for (int kpw = 0; kpw < KPW; ++kpw) {
        const floatx4 init = *(const floatx4*)(bias + (kogb + kpw) * 16 + q16 * 4);
#pragma unroll
        for (int p = 0; p < 16; ++p) acc[kpw][p] = init;
    }

    const short8* wtv = (const short8*)wt;
#pragma unroll
    for (int ch = 0; ch < CI / 32; ++ch) {
        short8 af[KPW][9];
#pragma unroll
        for (int t = 0; t < 9; ++t)
#pragma unroll
            for (int kpw = 0; kpw < KPW; ++kpw)
                af[kpw][t] = wtv[(size_t)(t * KO + (kogb + kpw) * 16 + c16) * (CI / 8)
                                 + ch * 4 + q16];
#pragma unroll
        for (int t = 0; t < 9; ++t) {
            const int dy = t / 3, dx = t - dy * 3;
#pragma unroll
            for (int p = 0; p < 16; ++p) {
                const int row = (p >> 2) + dy;
                const int col = (p & 3) * 16 + dx + c16;
                const short8 bf = lds[(row * 66 + col) * CG + ch * 4 + q16];
#pragma unroll
                for (int kpw = 0; kpw < KPW; ++kpw)
                    acc[kpw][p] = __builtin_amdgcn_mfma_f32_16x16x32_bf16(
                        af[kpw][t], bf, acc[kpw][p], 0, 0, 0);
            }
        }
    }

    // epilogue: C/D layout col(lane&15)=pixel, row(quad*4+reg)=ko offset
    u16* Yn = Y + (size_t)n * KO * 4096;
#pragma unroll
    for (int kpw = 0; kpw < KPW; ++kpw) {
        const int ko = (kogb + kpw) * 16 + q16 * 4;
#pragma unroll
        for (int p = 0; p < 16; ++p) {
            const int h = h0 + (p >> 2);
            const int w = (p & 3) * 16 + c16;
            u16* dst = Yn + (size_t)ko * 4096 + h * 64 + w;
#pragma unroll
            for (int r = 0; r < 4; ++r) dst[(size_t)r * 4096] = f2bits(acc[kpw][p][r]);
        }
    }
}

// ---- minGRU scan + residual, one batch, vec4, NO aliasing -----------------
// y (S,128,HW) bf16: gate ch c, hidden ch c+64. res (S,64,HW) bf16.
// out: bf16 (S,64,HW) if OUT_BF16 else f32. hlast (64,HW) f32 (pre-residual).
template<bool OUT_BF16>
__global__ void gru_kernel(const u16* y, const u16* res, void* outp, float* hlast) {
    const int e  = (blockIdx.x * 256 + threadIdx.x) * 4;  // over 64*4096
    const int c  = e >> 12;
    const int hw = e & 4095;
    float h[4] = {0.5f, 0.5f, 0.5f, 0.5f};
#pragma unroll
    for (int s = 0; s < SS; ++s) {
        const shortx4 g4 = *(const shortx4*)(y + (size_t)(s * 128 + c) * 4096 + hw);
        const shortx4 d4 = *(const shortx4*)(y + (size_t)(s * 128 + c + 64) * 4096 + hw);
        const shortx4 r4 = *(const shortx4*)(res + (size_t)(s * 64 + c) * 4096 + hw);
        float o[4];
#pragma unroll
        for (int j = 0; j < 4; ++j) {
            const float g   = bits2f((u16)g4[j]);
            const float hid = bits2f((u16)d4[j]);
            const float z   = 1.0f / (1.0f + __expf(-g));
            const float gg  = (hid >= 0.0f) ? (hid + 0.5f) : (1.0f / (1.0f + __expf(-hid)));
            h[j] = h[j] + z * (gg - h[j]);             // (1-z)*h + z*gg
            o[j] = h[j] + bits2f((u16)r4[j]);
        }
        if (OUT_BF16) {
            shortx4 ov;
#pragma unroll
            for (int j = 0; j < 4; ++j) ov[j] = (short)f2bits(o[j]);
            *(shortx4*)((u16*)outp + (size_t)(s * 64 + c) * 4096 + hw) = ov;
        } else {
            floatx4 ov;
#pragma unroll
            for (int j = 0; j < 4; ++j) ov[j] = o[j];
            *(floatx4*)((float*)outp + (size_t)(s * 64 + c) * 4096 + hw) = ov;
        }
    }
    floatx4 hv;
#pragma unroll
    for (int j = 0; j < 4; ++j) hv[j] = h[j];
    *(floatx4*)(hlast + (size_t)e) = hv;
}

extern "C" void kernel_launch(void* const* d_in, const int* in_sizes, int n_in,
                              void* d_out, int out_size, void* d_ws, size_t ws_size,
                              hipStream_t stream) {
    const float* x  = (const float*)d_in[0];   // (4,16,32,64,64)
    const float* W0 = (const float*)d_in[1];   // (128,32,3,3)
    const float* b0 = (const float*)d_in[2];   // (128,)
    const float* R0 = (const float*)d_in[3];   // (64,32,3,3)
    const float* W1 = (const float*)d_in[4];   // (128,64,3,3)
    const float* b1 = (const float*)d_in[5];   // (128,)

    float* out = (float*)d_out;                 // (4,16,64,64,64)
    float* h0o = out + (size_t)16777216;
    float* h1o = h0o + (size_t)1048576;

    char* ws = (char*)d_ws;
    u16*   wt0 = (u16*)ws;                                 // 73,728 B
    u16*   wtR = (u16*)(ws + 73728);                       // 36,864 B
    u16*   wt1 = (u16*)(ws + 110592);                      // 147,456 B
    float* zb  = (float*)(ws + 258048);                    // 256 B
    u16*   y0  = (u16*)(ws + (size_t)(1  << 20));          // 16 MiB
    u16*   r0  = (u16*)(ws + (size_t)(17 << 20));          // 8 MiB
    u16*   x1  = (u16*)(ws + (size_t)(25 << 20));          // 8 MiB -> ends 33 MiB

    prep_kernel<<<505, 256, 0, stream>>>(W0, R0, W1, wt0, wtR, wt1, zb);

    for (int b = 0; b < 4; ++b) {
        const float* xb = x + (size_t)b * SS * 32 * 4096;

        // Layer 0: gate/hidden conv + residual conv + scan -> x1
        conv3x3_mfma_kernel<float, 32, 128><<<dim3(16, SS), 256, 0, stream>>>(xb, wt0, b0, y0);
        conv3x3_mfma_kernel<float, 32, 64><<<dim3(16, SS), 256, 0, stream>>>(xb, wtR, zb, r0);
        gru_kernel<true><<<256, 256, 0, stream>>>(y0, r0, x1, h0o + (size_t)b * 262144);

        // Layer 1: conv from x1 -> y0, identity residual (= x1)
        conv3x3_mfma_kernel<u16, 64, 128><<<dim3(16, SS), 256, 0, stream>>>(x1, wt1, b1, y0);
        gru_kernel<false><<<256, 256, 0, stream>>>(y0, x1,
                                                   out + (size_t)b * 4194304,
                                                   h1o + (size_t)b * 262144);
    }
}

// Round 8
// 370.040 us; speedup vs baseline: 24.6421x; 1.3586x over previous
//
#include <hip/hip_runtime.h>

typedef short short8  __attribute__((ext_vector_type(8)));
typedef short shortx4 __attribute__((ext_vector_type(4)));
typedef float floatx4 __attribute__((ext_vector_type(4)));
typedef unsigned short u16;

static __device__ __forceinline__ float bits2f(u16 s) {
    return __builtin_bit_cast(float, (unsigned)s << 16);
}
static __device__ __forceinline__ u16 f2bits(float f) {
    return __builtin_bit_cast(u16, (__bf16)f);   // RNE
}

#define SS 16

// ---- weight prepack: wt[tap][ko][ci] bf16 + 64-entry zero bias ------------
__global__ void prep_kernel(const float* W0, const float* R0, const float* W1,
                            u16* wt0, u16* wtR, u16* wt1, float* zb) {
    const int i = blockIdx.x * 256 + threadIdx.x;
    if (i < 36864) {
        const int t = i / 4096, r = i % 4096, ko = r >> 5, ci = r & 31;
        wt0[i] = f2bits(W0[(ko * 32 + ci) * 9 + t]);
    } else if (i < 36864 + 18432) {
        const int j = i - 36864;
        const int t = j / 2048, r = j % 2048, ko = r >> 5, ci = r & 31;
        wtR[j] = f2bits(R0[(ko * 32 + ci) * 9 + t]);
    } else if (i < 36864 + 18432 + 73728) {
        const int j = i - 36864 - 18432;
        const int t = j / 8192, r = j % 8192, ko = r >> 6, ci = r & 63;
        wt1[j] = f2bits(W1[(ko * 64 + ci) * 9 + t]);
    } else if (i < 36864 + 18432 + 73728 + 64) {
        zb[i - 129024] = 0.0f;
    }
}

// ---- x (64,32,64,64) f32 NCHW -> xT (64,64,64,32) bf16 NHWC ---------------
// block = one (img,h): 256 thr = 64 w x 4 ci-granules. grid 4096.
__global__ void transpose_kernel(const float* __restrict__ x, u16* __restrict__ xT) {
    const int img = blockIdx.x >> 6, h = blockIdx.x & 63;
    const int gq = threadIdx.x & 3, w = threadIdx.x >> 2;
    short8 o;
#pragma unroll
    for (int k = 0; k < 8; ++k)
        o[k] = (short)f2bits(x[((size_t)img * 32 + gq * 8 + k) * 4096 + h * 64 + w]);
    ((short8*)xT)[((size_t)(img * 64 + h) * 64 + w) * 4 + gq] = o;
}

// ---- MFMA implicit-GEMM 3x3 conv, pad 1, NHWC -----------------------------
// X (64,64,64,CI) bf16 NHWC; wt [9][KO][CI] bf16; bias (KO) f32;
// Y (64,64,64,KO) bf16 NHWC. Block 256 = 4 waves; one image x 4-row strip.
// grid(16 strips, 64 img). Wave: KPW=KO/64 ko-groups x 16 pixel-groups.
template<int CI, int KO>
__global__ __launch_bounds__(256, 2)
void conv3x3_mfma_kernel(const u16* __restrict__ X, const u16* __restrict__ wt,
                         const float* __restrict__ bias, u16* __restrict__ Y) {
    constexpr int CG  = CI / 8;            // 16B ci-granules per pixel
    constexpr int CGS = (CG == 4) ? 2 : 3; // log2(CG)
    constexpr int KPW = KO / 64;
    __shared__ short8 lds[6 * 66 * CG];

    const int l   = threadIdx.x & 63;
    const int wv  = threadIdx.x >> 6;
    const int c16 = l & 15;
    const int q16 = l >> 4;
    const int h0  = blockIdx.x * 4;
    const int n   = blockIdx.y;

    // zero LDS (borders + out-of-range rows stay zero)
    {
        const short8 z = {0, 0, 0, 0, 0, 0, 0, 0};
        for (int i = threadIdx.x; i < 6 * 66 * CG; i += 256) lds[i] = z;
    }
    __syncthreads();

    // stage rows h0-1..h0+4: contiguous 16B granule loads + swizzled ds_write
    // task = (row, chunk); chunk = 64 lanes = 64/CG cols x CG granules
    const short8* Xg = (const short8*)X;
    for (int task = wv; task < 6 * CG; task += 4) {
        const int r     = task >> CGS;          // 6*CG tasks / CG chunks-per-row
        const int chunk = task & (CG - 1);
        const int h     = h0 + r - 1;
        if (h >= 0 && h < 64) {
            const int colrel = chunk * (64 / CG) + (l >> CGS);
            const int q      = l & (CG - 1);
            const int col    = 1 + colrel;
            const short8 v = Xg[((size_t)(n * 64 + h) * 64 + colrel) * CG + q];
            lds[(r * 66 + col) * CG + ((q + col) & (CG - 1))] = v;
        }
    }
    __syncthreads();

    const int kogb = wv * KPW;
    floatx4 acc[KPW][16];
#pragma unroll
    for (int kpw = 0; kpw < KPW; ++kpw) {
        const floatx4 init = *(const floatx4*)(bias + (kogb + kpw) * 16 + q16 * 4);
#pragma unroll
        for (int p = 0; p < 16; ++p) acc[kpw][p] = init;
    }

    const short8* wtv = (const short8*)wt;
#pragma unroll
    for (int ch = 0; ch < CI / 32; ++ch) {
        short8 af[KPW][9];
#pragma unroll
        for (int t = 0; t < 9; ++t)
#pragma unroll
            for (int kpw = 0; kpw < KPW; ++kpw)
                af[kpw][t] = wtv[(size_t)(t * KO + (kogb + kpw) * 16 + c16) * CG
                                 + ch * 4 + q16];
#pragma unroll
        for (int t = 0; t < 9; ++t) {
            const int dy = t / 3, dx = t - dy * 3;
#pragma unroll
            for (int p = 0; p < 16; ++p) {
                const int row = (p >> 2) + dy;
                const int col = (p & 3) * 16 + dx + c16;
                const int q   = ch * 4 + q16;
                const short8 bf = lds[(row * 66 + col) * CG + ((q + col) & (CG - 1))];
#pragma unroll
                for (int kpw = 0; kpw < KPW; ++kpw)
                    acc[kpw][p] = __builtin_amdgcn_mfma_f32_16x16x32_bf16(
                        af[kpw][t], bf, acc[kpw][p], 0, 0, 0);
            }
        }
    }

    // NHWC epilogue: reg r = consecutive ko -> bf16x4 8B stores
#pragma unroll
    for (int kpw = 0; kpw < KPW; ++kpw) {
        const int kob = (kogb + kpw) * 16 + q16 * 4;
#pragma unroll
        for (int p = 0; p < 16; ++p) {
            const int h = h0 + (p >> 2);
            const int w = (p & 3) * 16 + c16;
            shortx4 ov;
#pragma unroll
            for (int r = 0; r < 4; ++r) ov[r] = (short)f2bits(acc[kpw][p][r]);
            ((shortx4*)Y)[((size_t)(n * 64 + h) * 64 + w) * (KO / 4) + (kob >> 2)] = ov;
        }
    }
}

// ---- minGRU scan + residual, full batch, NHWC -----------------------------
// Yg (64,4096,128) bf16 NHWC: gate ch [0,64), hidden [64,128). R (64,4096,64).
// FINAL=0: out = x1 bf16 NHWC. FINAL=1: out = f32 NCHW (B,S,64,HW) via LDS
// transpose. hlast (B,64,HW) f32 = scan at s=S-1. Block: 16 hw x 16 cg.
template<bool FINAL>
__global__ void gru_kernel(const u16* __restrict__ Yg, const u16* __restrict__ R,
                           void* __restrict__ outp, float* __restrict__ hlast) {
    __shared__ float lds_t[16 * 68];
    const int cg  = threadIdx.x & 15;
    const int hwl = threadIdx.x >> 4;
    const int b   = blockIdx.x >> 8;
    const int hwh = blockIdx.x & 255;
    const int hw  = hwh * 16 + hwl;
    const shortx4* Yv = (const shortx4*)Yg;
    const shortx4* Rv = (const shortx4*)R;
    float h[4] = {0.5f, 0.5f, 0.5f, 0.5f};
#pragma unroll
    for (int s = 0; s < SS; ++s) {
        const size_t px = (size_t)(b * 16 + s) * 4096 + hw;
        const shortx4 g4 = Yv[px * 32 + cg];
        const shortx4 d4 = Yv[px * 32 + 16 + cg];
        const shortx4 r4 = Rv[px * 16 + cg];
        float o[4];
#pragma unroll
        for (int j = 0; j < 4; ++j) {
            const float g   = bits2f((u16)g4[j]);
            const float hid = bits2f((u16)d4[j]);
            const float z   = 1.0f / (1.0f + __expf(-g));
            const float gg  = (hid >= 0.0f) ? (hid + 0.5f) : (1.0f / (1.0f + __expf(-hid)));
            h[j] = h[j] + z * (gg - h[j]);             // (1-z)*h + z*gg
            o[j] = h[j] + bits2f((u16)r4[j]);
        }
        if (!FINAL) {
            shortx4 ov;
#pragma unroll
            for (int j = 0; j < 4; ++j) ov[j] = (short)f2bits(o[j]);
            ((shortx4*)outp)[px * 16 + cg] = ov;
        } else {
            // NHWC (thread-local 4 ch) -> NCHW f32 via padded LDS tile
            floatx4 o4; 
#pragma unroll
            for (int j = 0; j < 4; ++j) o4[j] = o[j];
            *(floatx4*)(&lds_t[hwl * 68 + cg * 4]) = o4;
            __syncthreads();
            const int c2 = threadIdx.x >> 2, h4 = threadIdx.x & 3;
            floatx4 v;
#pragma unroll
            for (int k = 0; k < 4; ++k) v[k] = lds_t[(h4 * 4 + k) * 68 + c2];
            *(floatx4*)((float*)outp +
                        ((size_t)(b * 16 + s) * 64 + c2) * 4096 + hwh * 16 + h4 * 4) = v;
            __syncthreads();
        }
    }
#pragma unroll
    for (int j = 0; j < 4; ++j)
        hlast[((size_t)b * 64 + cg * 4 + j) * 4096 + hw] = h[j];
}

extern "C" void kernel_launch(void* const* d_in, const int* in_sizes, int n_in,
                              void* d_out, int out_size, void* d_ws, size_t ws_size,
                              hipStream_t stream) {
    const float* x  = (const float*)d_in[0];   // (4,16,32,64,64)
    const float* W0 = (const float*)d_in[1];   // (128,32,3,3)
    const float* b0 = (const float*)d_in[2];   // (128,)
    const float* R0 = (const float*)d_in[3];   // (64,32,3,3)
    const float* W1 = (const float*)d_in[4];   // (128,64,3,3)
    const float* b1 = (const float*)d_in[5];   // (128,)

    float* out = (float*)d_out;                 // (4,16,64,64,64) NCHW f32
    float* h0o = out + (size_t)16777216;
    float* h1o = h0o + (size_t)1048576;

    char* ws = (char*)d_ws;
    u16*   wt0 = (u16*)ws;                              // 73,728 B
    u16*   wtR = (u16*)(ws + 73728);                    // 36,864 B
    u16*   wt1 = (u16*)(ws + 110592);                   // 147,456 B
    float* zb  = (float*)(ws + 258048);                 // 256 B
    u16*   xT  = (u16*)(ws + (size_t)(1  << 20));       // 16 MiB (NHWC bf16 input)
    u16*   x1  = xT;                                    // 32 MiB; overwrites xT after convs
    u16*   y0  = (u16*)(ws + (size_t)(33 << 20));       // 64 MiB (NHWC 128ch)
    u16*   r0  = (u16*)(ws + (size_t)(97 << 20));       // 32 MiB (NHWC 64ch) -> ends 129 MiB

    prep_kernel<<<505, 256, 0, stream>>>(W0, R0, W1, wt0, wtR, wt1, zb);
    transpose_kernel<<<4096, 256, 0, stream>>>(x, xT);

    // Layer 0 (full batch): gate/hidden conv + residual conv + scan -> x1
    conv3x3_mfma_kernel<32, 128><<<dim3(16, 64), 256, 0, stream>>>(xT, wt0, b0, y0);
    conv3x3_mfma_kernel<32, 64 ><<<dim3(16, 64), 256, 0, stream>>>(xT, wtR, zb, r0);
    gru_kernel<false><<<1024, 256, 0, stream>>>(y0, r0, x1, h0o);

    // Layer 1: conv from x1 -> y0 (reuse), scan with identity residual -> out
    conv3x3_mfma_kernel<64, 128><<<dim3(16, 64), 256, 0, stream>>>(x1, wt1, b1, y0);
    gru_kernel<true ><<<1024, 256, 0, stream>>>(y0, x1, out, h1o);
}

// Round 9
// 319.458 us; speedup vs baseline: 28.5439x; 1.1583x over previous
//
#include <hip/hip_runtime.h>

typedef short short8  __attribute__((ext_vector_type(8)));
typedef short shortx4 __attribute__((ext_vector_type(4)));
typedef float floatx4 __attribute__((ext_vector_type(4)));
typedef unsigned short u16;

static __device__ __forceinline__ float bits2f(u16 s) {
    return __builtin_bit_cast(float, (unsigned)s << 16);
}
static __device__ __forceinline__ u16 f2bits(float f) {
    return __builtin_bit_cast(u16, (__bf16)f);   // RNE
}

#define SS 16

// ---- weight prepack: wt[tap][ko][ci] bf16 + 64-entry zero bias ------------
__global__ void prep_kernel(const float* W0, const float* R0, const float* W1,
                            u16* wt0, u16* wtR, u16* wt1, float* zb) {
    const int i = blockIdx.x * 256 + threadIdx.x;
    if (i < 36864) {
        const int t = i / 4096, r = i % 4096, ko = r >> 5, ci = r & 31;
        wt0[i] = f2bits(W0[(ko * 32 + ci) * 9 + t]);
    } else if (i < 36864 + 18432) {
        const int j = i - 36864;
        const int t = j / 2048, r = j % 2048, ko = r >> 5, ci = r & 31;
        wtR[j] = f2bits(R0[(ko * 32 + ci) * 9 + t]);
    } else if (i < 36864 + 18432 + 73728) {
        const int j = i - 36864 - 18432;
        const int t = j / 8192, r = j % 8192, ko = r >> 6, ci = r & 63;
        wt1[j] = f2bits(W1[(ko * 64 + ci) * 9 + t]);
    } else if (i < 36864 + 18432 + 73728 + 64) {
        zb[i - 129024] = 0.0f;
    }
}

// ---- x (64,32,64,64) f32 NCHW -> xT (64,64,64,32) bf16 NHWC ---------------
__global__ void transpose_kernel(const float* __restrict__ x, u16* __restrict__ xT) {
    const int img = blockIdx.x >> 6, h = blockIdx.x & 63;
    const int gq = threadIdx.x & 3, w = threadIdx.x >> 2;
    short8 o;
#pragma unroll
    for (int k = 0; k < 8; ++k)
        o[k] = (short)f2bits(x[((size_t)img * 32 + gq * 8 + k) * 4096 + h * 64 + w]);
    ((short8*)xT)[((size_t)(img * 64 + h) * 64 + w) * 4 + gq] = o;
}

// ---- MFMA implicit-GEMM 3x3 conv, pad 1, NHWC -----------------------------
// X (64,64,64,CI) bf16 NHWC; wt [9][KO][CI] bf16; bias (KO) f32;
// Y (64,64,64,KO) bf16 NHWC. Block 256 = 4 waves; one image x 4-row strip.
// grid(16 strips, 64 img). Epilogue: LDS transpose -> coalesced nt stores.
template<int CI, int KO>
__global__ __launch_bounds__(256, 2)
void conv3x3_mfma_kernel(const u16* __restrict__ X, const u16* __restrict__ wt,
                         const float* __restrict__ bias, u16* __restrict__ Y) {
    constexpr int CG  = CI / 8;            // 16B ci-granules per pixel
    constexpr int CGS = (CG == 4) ? 2 : 3; // log2(CG)
    constexpr int KPW = KO / 64;
    constexpr int NG  = KO / 8;            // 16B ko-granules per pixel (out)
    constexpr int PXS = NG + 1;            // padded pixel stride (granules)
    constexpr int SG  = 6 * 66 * CG;       // staging granules
    constexpr int EPG = 128 * PXS;         // epilogue granules (2 rows x 64 px)
    constexpr int LSZ = (SG > EPG) ? SG : EPG;
    __shared__ short8 lds[LSZ];

    const int l   = threadIdx.x & 63;
    const int wv  = threadIdx.x >> 6;
    const int c16 = l & 15;
    const int q16 = l >> 4;
    const int h0  = blockIdx.x * 4;
    const int n   = blockIdx.y;

    // zero staging LDS (borders + out-of-range rows stay zero)
    {
        const short8 z = {0, 0, 0, 0, 0, 0, 0, 0};
        for (int i = threadIdx.x; i < SG; i += 256) lds[i] = z;
    }
    __syncthreads();

    // stage rows h0-1..h0+4: contiguous 16B granule loads + swizzled ds_write
    const short8* Xg = (const short8*)X;
    for (int task = wv; task < 6 * CG; task += 4) {
        const int r     = task >> CGS;
        const int chunk = task & (CG - 1);
        const int h     = h0 + r - 1;
        if (h >= 0 && h < 64) {
            const int colrel = chunk * (64 / CG) + (l >> CGS);
            const int q      = l & (CG - 1);
            const int col    = 1 + colrel;
            const short8 v = Xg[((size_t)(n * 64 + h) * 64 + colrel) * CG + q];
            lds[(r * 66 + col) * CG + ((q + col) & (CG - 1))] = v;
        }
    }
    __syncthreads();

    const int kogb = wv * KPW;
    floatx4 acc[KPW][16];
#pragma unroll
    for (int kpw = 0; kpw < KPW; ++kpw) {
        const floatx4 init = *(const floatx4*)(bias + (kogb + kpw) * 16 + q16 * 4);
#pragma unroll
        for (int p = 0; p < 16; ++p) acc[kpw][p] = init;
    }

    const short8* wtv = (const short8*)wt;
#pragma unroll
    for (int ch = 0; ch < CI / 32; ++ch) {
        short8 af[KPW][9];
#pragma unroll
        for (int t = 0; t < 9; ++t)
#pragma unroll
            for (int kpw = 0; kpw < KPW; ++kpw)
                af[kpw][t] = wtv[(size_t)(t * KO + (kogb + kpw) * 16 + c16) * CG
                                 + ch * 4 + q16];
#pragma unroll
        for (int t = 0; t < 9; ++t) {
            const int dy = t / 3, dx = t - dy * 3;
#pragma unroll
            for (int p = 0; p < 16; ++p) {
                const int row = (p >> 2) + dy;
                const int col = (p & 3) * 16 + dx + c16;
                const int q   = ch * 4 + q16;
                const short8 bf = lds[(row * 66 + col) * CG + ((q + col) & (CG - 1))];
#pragma unroll
                for (int kpw = 0; kpw < KPW; ++kpw)
                    acc[kpw][p] = __builtin_amdgcn_mfma_f32_16x16x32_bf16(
                        af[kpw][t], bf, acc[kpw][p], 0, 0, 0);
            }
        }
    }

    // epilogue: 2 rows at a time through LDS, then fully-coalesced nt stores
    shortx4* lq = (shortx4*)lds;
#pragma unroll
    for (int rp = 0; rp < 2; ++rp) {
        __syncthreads();   // staging (rp=0) / previous readback (rp=1) done
#pragma unroll
        for (int kpw = 0; kpw < KPW; ++kpw) {
            const int qoff = (kogb + kpw) * 4 + q16;
#pragma unroll
            for (int pp = 0; pp < 8; ++pp) {
                const int p   = rp * 8 + pp;
                const int pxl = ((p >> 2) & 1) * 64 + (p & 3) * 16 + c16;
                shortx4 ov;
#pragma unroll
                for (int r = 0; r < 4; ++r) ov[r] = (short)f2bits(acc[kpw][p][r]);
                lq[pxl * (2 * PXS) + qoff] = ov;
            }
        }
        __syncthreads();
#pragma unroll
        for (int i = 0; i < NG / 2; ++i) {
            const int L  = i * 256 + threadIdx.x;
            const int px = L / NG, g = L % NG;
            const int h  = h0 + 2 * rp + (px >> 6);
            const int w  = px & 63;
            const short8 v = lds[px * PXS + g];
            __builtin_nontemporal_store(
                v, (short8*)Y + ((size_t)(n * 64 + h) * 64 + w) * NG + g);
        }
    }
}

// ---- minGRU scan + residual, full batch, NHWC -----------------------------
// Yg (64,4096,128) bf16 NHWC: gate ch [0,64), hidden [64,128). R (64,4096,64).
// FINAL=0: out = x1 bf16 NHWC. FINAL=1: out = f32 NCHW via LDS transpose.
// hlast (B,64,HW) f32 via LDS transpose. Block: 16 hw x 16 cg.
template<bool FINAL>
__global__ void gru_kernel(const u16* __restrict__ Yg, const u16* __restrict__ R,
                           void* __restrict__ outp, float* __restrict__ hlast) {
    __shared__ float lds_t[16 * 68];
    const int cg  = threadIdx.x & 15;
    const int hwl = threadIdx.x >> 4;
    const int b   = blockIdx.x >> 8;
    const int hwh = blockIdx.x & 255;
    const int hw  = hwh * 16 + hwl;
    const shortx4* Yv = (const shortx4*)Yg;
    const shortx4* Rv = (const shortx4*)R;
    float h[4] = {0.5f, 0.5f, 0.5f, 0.5f};
#pragma unroll
    for (int s = 0; s < SS; ++s) {
        const size_t px = (size_t)(b * 16 + s) * 4096 + hw;
        const shortx4 g4 = Yv[px * 32 + cg];
        const shortx4 d4 = Yv[px * 32 + 16 + cg];
        const shortx4 r4 = Rv[px * 16 + cg];
        float o[4];
#pragma unroll
        for (int j = 0; j < 4; ++j) {
            const float g   = bits2f((u16)g4[j]);
            const float hid = bits2f((u16)d4[j]);
            const float z   = 1.0f / (1.0f + __expf(-g));
            const float gg  = (hid >= 0.0f) ? (hid + 0.5f) : (1.0f / (1.0f + __expf(-hid)));
            h[j] = h[j] + z * (gg - h[j]);             // (1-z)*h + z*gg
            o[j] = h[j] + bits2f((u16)r4[j]);
        }
        if (!FINAL) {
            shortx4 ov;
#pragma unroll
            for (int j = 0; j < 4; ++j) ov[j] = (short)f2bits(o[j]);
            ((shortx4*)outp)[px * 16 + cg] = ov;
        } else {
            floatx4 o4;
#pragma unroll
            for (int j = 0; j < 4; ++j) o4[j] = o[j];
            *(floatx4*)(&lds_t[hwl * 68 + cg * 4]) = o4;
            __syncthreads();
            const int c2 = threadIdx.x >> 2, h4 = threadIdx.x & 3;
            floatx4 v;
#pragma unroll
            for (int k = 0; k < 4; ++k) v[k] = lds_t[(h4 * 4 + k) * 68 + c2];
            *(floatx4*)((float*)outp +
                        ((size_t)(b * 16 + s) * 64 + c2) * 4096 + hwh * 16 + h4 * 4) = v;
            __syncthreads();
        }
    }
    // hlast: per-thread NHWC regs -> NCHW f32 via LDS transpose (64B segments)
    {
        floatx4 h4v;
#pragma unroll
        for (int j = 0; j < 4; ++j) h4v[j] = h[j];
        if (!FINAL) __syncthreads();   // FINAL path already synced at loop end
        *(floatx4*)(&lds_t[hwl * 68 + cg * 4]) = h4v;
        __syncthreads();
        const int c2 = threadIdx.x >> 2, h4 = threadIdx.x & 3;
        floatx4 v;
#pragma unroll
        for (int k = 0; k < 4; ++k) v[k] = lds_t[(h4 * 4 + k) * 68 + c2];
        *(floatx4*)(hlast + ((size_t)b * 64 + c2) * 4096 + hwh * 16 + h4 * 4) = v;
    }
}

extern "C" void kernel_launch(void* const* d_in, const int* in_sizes, int n_in,
                              void* d_out, int out_size, void* d_ws, size_t ws_size,
                              hipStream_t stream) {
    const float* x  = (const float*)d_in[0];   // (4,16,32,64,64)
    const float* W0 = (const float*)d_in[1];   // (128,32,3,3)
    const float* b0 = (const float*)d_in[2];   // (128,)
    const float* R0 = (const float*)d_in[3];   // (64,32,3,3)
    const float* W1 = (const float*)d_in[4];   // (128,64,3,3)
    const float* b1 = (const float*)d_in[5];   // (128,)

    float* out = (float*)d_out;                 // (4,16,64,64,64) NCHW f32
    float* h0o = out + (size_t)16777216;
    float* h1o = h0o + (size_t)1048576;

    char* ws = (char*)d_ws;
    u16*   wt0 = (u16*)ws;                              // 73,728 B
    u16*   wtR = (u16*)(ws + 73728);                    // 36,864 B
    u16*   wt1 = (u16*)(ws + 110592);                   // 147,456 B
    float* zb  = (float*)(ws + 258048);                 // 256 B
    u16*   xT  = (u16*)(ws + (size_t)(1  << 20));       // 16 MiB (NHWC bf16 input)
    u16*   x1  = xT;                                    // 32 MiB; overwrites xT after convs
    u16*   y0  = (u16*)(ws + (size_t)(33 << 20));       // 64 MiB (NHWC 128ch)
    u16*   r0  = (u16*)(ws + (size_t)(97 << 20));       // 32 MiB (NHWC 64ch) -> ends 129 MiB

    prep_kernel<<<505, 256, 0, stream>>>(W0, R0, W1, wt0, wtR, wt1, zb);
    transpose_kernel<<<4096, 256, 0, stream>>>(x, xT);

    // Layer 0 (full batch): gate/hidden conv + residual conv + scan -> x1
    conv3x3_mfma_kernel<32, 128><<<dim3(16, 64), 256, 0, stream>>>(xT, wt0, b0, y0);
    conv3x3_mfma_kernel<32, 64 ><<<dim3(16, 64), 256, 0, stream>>>(xT, wtR, zb, r0);
    gru_kernel<false><<<1024, 256, 0, stream>>>(y0, r0, x1, h0o);

    // Layer 1: conv from x1 -> y0 (reuse), scan with identity residual -> out
    conv3x3_mfma_kernel<64, 128><<<dim3(16, 64), 256, 0, stream>>>(x1, wt1, b1, y0);
    gru_kernel<true ><<<1024, 256, 0, stream>>>(y0, x1, out, h1o);
}